// Round 1
// baseline (161.186 us; speedup 1.0000x reference)
//
#include <hip/hip_runtime.h>
#include <math.h>

// Problem constants (fixed-shape problem: B=4, H=64, W=64, N=64, HID=64)
#define Nn    64
#define RPB   4                 // rays (waves) per 256-thread block
#define NRAYS 16384             // 4*64*64
#define NEARV 2.0f
#define FARV  6.0f

__device__ __forceinline__ float scan_mul(float p, int lane) {
#pragma unroll
  for (int off = 1; off < 64; off <<= 1) {
    float t = __shfl_up(p, off, 64);
    if (lane >= off) p *= t;
  }
  return p;
}

__device__ __forceinline__ float scan_add(float v, int lane) {
#pragma unroll
  for (int off = 1; off < 64; off <<= 1) {
    float t = __shfl_up(v, off, 64);
    if (lane >= off) v += t;
  }
  return v;
}

__device__ __forceinline__ float reduce_add(float v) {
#pragma unroll
  for (int off = 32; off > 0; off >>= 1) v += __shfl_xor(v, off, 64);
  return v;
}

__device__ __forceinline__ float sigmoidf(float x) {
  return 1.f / (1.f + expf(-x));
}

// Tiny MLP eval at depth z using per-ray rank-1 precompute rec[j] = {c0,c1,W2[j][0..3],pad,pad}
__device__ __forceinline__ void mlp_eval(const float* __restrict__ rec, float z,
                                         float bb0, float bb1, float bb2, float bb3,
                                         float& sig, float& r, float& g, float& b) {
  float a0 = bb0, a1 = bb1, a2 = bb2, a3 = bb3;
#pragma unroll 16
  for (int j = 0; j < 64; ++j) {
    const float4 q  = *reinterpret_cast<const float4*>(rec + j * 8);
    const float2 q2 = *reinterpret_cast<const float2*>(rec + j * 8 + 4);
    float h = fmaf(z, q.y, q.x);   // z*c1 + c0
    h = fmaxf(h, 0.f);             // relu
    a0 = fmaf(h, q.z, a0);
    a1 = fmaf(h, q.w, a1);
    a2 = fmaf(h, q2.x, a2);
    a3 = fmaf(h, q2.y, a3);
  }
  sig = a0;
  r = sigmoidf(a1);
  g = sigmoidf(a2);
  b = sigmoidf(a3);
}

__global__ __launch_bounds__(RPB * 64) void nerf_fused(
    const float* __restrict__ ray_o, const float* __restrict__ ray_d,
    const float* __restrict__ tform, const float* __restrict__ noise,
    const float* __restrict__ usmp,  const float* __restrict__ W1,
    const float* __restrict__ b1,    const float* __restrict__ W2,
    const float* __restrict__ b2,    float* __restrict__ out) {
  const int wave = threadIdx.x >> 6;
  const int lane = threadIdx.x & 63;
  const int ray  = blockIdx.x * RPB + wave;

  __shared__ float sRec[RPB][Nn][8];       // per-ray MLP records
  __shared__ float sZ  [RPB][2 * Nn];      // unsorted z (coarse|fine)
  __shared__ float sZs [RPB][2 * Nn];      // sorted z
  __shared__ float sSg [RPB][2 * Nn];      // sorted sigma
  __shared__ float sRg [RPB][2 * Nn * 3];  // sorted rgb
  __shared__ float sCdf[RPB][Nn];          // cdf (63 valid entries)
  __shared__ float sBin[RPB][Nn];          // z_mid bins (63 valid entries)

  // ---- per-ray constants ----
  const float o0 = ray_o[ray * 3 + 0];
  const float o1 = ray_o[ray * 3 + 1];
  const float o2 = ray_o[ray * 3 + 2];
  float d0 = ray_d[ray * 3 + 0];
  float d1 = ray_d[ray * 3 + 1];
  float d2 = ray_d[ray * 3 + 2];
  const float nrm = sqrtf(d0 * d0 + d1 * d1 + d2 * d2);
  d0 /= nrm; d1 /= nrm; d2 /= nrm;

  // rank-1 MLP precompute: h_j(z) = relu(z*c1[j] + c0[j]); lane j builds record j
  {
    const float w10 = W1[lane], w11 = W1[64 + lane], w12 = W1[128 + lane];
    const float c1 = d0 * w10 + d1 * w11 + d2 * w12;
    const float c0 = o0 * w10 + o1 * w11 + o2 * w12 + b1[lane];
    const float4 w2r = *reinterpret_cast<const float4*>(W2 + lane * 4);
    float* rec = &sRec[wave][lane][0];
    rec[0] = c0;   rec[1] = c1;
    rec[2] = w2r.x; rec[3] = w2r.y; rec[4] = w2r.z; rec[5] = w2r.w;
  }
  const float bb0 = b2[0], bb1 = b2[1], bb2v = b2[2], bb3 = b2[3];
  __syncthreads();

  const float* rec = &sRec[wave][0][0];

  // ---- coarse samples: lane = sample index ----
  const float nz = noise[ray * Nn + lane];
  const float z  = NEARV + (FARV - NEARV) * ((float)lane + nz) * (1.0f / Nn);

  float sig, cr, cg, cb;
  mlp_eval(rec, z, bb0, bb1, bb2v, bb3, sig, cr, cg, cb);

  // ---- coarse compositing weights (wave-scan cumprod) ----
  const float zn   = __shfl_down(z, 1, 64);
  const float dist = (lane == 63) ? 1e10f : (zn - z);
  const float alpha = 1.f - expf(-fmaxf(sig, 0.f) * dist);
  {
    float P  = scan_mul(1.f - alpha + 1e-10f, lane);
    float Te = __shfl_up(P, 1, 64);
    if (lane == 0) Te = 1.f;
    const float w = alpha * Te;

    // ---- max/avg pool smoothing: sm[i] = 0.5*(mx[i]+mx[i+1]) + 0.01 ----
    const float wp = __shfl_up(w, 1, 64);
    const float wn = __shfl_down(w, 1, 64);
    const float mxA = (lane == 0)  ? w : fmaxf(wp, w);
    const float mxB = (lane == 63) ? w : fmaxf(w, wn);
    const float sm = 0.5f * (mxA + mxB) + 0.01f;

    // pdf over sm[1..62]; cdf[0]=0, cdf[k]=cumsum (63 entries)
    const float v   = (lane >= 1 && lane <= 62) ? sm : 0.f;
    const float tot = reduce_add(v);
    const float pdf = v / tot;
    const float C   = scan_add(pdf, lane);
    sCdf[wave][lane] = (lane == 0) ? 0.f : C;
    sBin[wave][lane] = 0.5f * (z + zn);   // z_mid; lane 63 entry never read
  }
  __syncthreads();

  // ---- inverse-CDF importance sampling (searchsorted side='right') ----
  const float u = usmp[ray * Nn + lane];
  int lo = 0, hi = 63;
  while (lo < hi) {
    const int mid = (lo + hi) >> 1;
    if (sCdf[wave][mid] <= u) lo = mid + 1; else hi = mid;
  }
  const int below = lo - 1;                 // in [0,62]
  const int above = (lo < 63) ? lo : 62;    // clip to 62
  const float cdfb = sCdf[wave][below], cdfa = sCdf[wave][above];
  const float binb = sBin[wave][below], bina = sBin[wave][above];
  float den = cdfa - cdfb;
  if (den < 1e-5f) den = 1.f;
  const float tt = (u - cdfb) / den;
  const float zs = fmaf(tt, bina - binb, binb);

  // ---- fine MLP eval ----
  float sigF, fr, fg, fb;
  mlp_eval(rec, zs, bb0, bb1, bb2v, bb3, sigF, fr, fg, fb);

  // ---- stable rank-sort of 2N=128 depths ----
  sZ[wave][lane]      = z;
  sZ[wave][64 + lane] = zs;
  __syncthreads();
  int r0 = 0, r1 = 0;
#pragma unroll 8
  for (int j = 0; j < 128; ++j) {
    const float zj = sZ[wave][j];
    r0 += (zj < z)  || (zj == z  && j < lane);
    r1 += (zj < zs) || (zj == zs && j < 64 + lane);
  }
  sZs[wave][r0] = z;  sSg[wave][r0] = sig;
  sRg[wave][r0 * 3 + 0] = cr; sRg[wave][r0 * 3 + 1] = cg; sRg[wave][r0 * 3 + 2] = cb;
  sZs[wave][r1] = zs; sSg[wave][r1] = sigF;
  sRg[wave][r1 * 3 + 0] = fr; sRg[wave][r1 * 3 + 1] = fg; sRg[wave][r1 * 3 + 2] = fb;
  __syncthreads();

  // ---- final compositing over 128 sorted samples (2 per lane) ----
  const int e0 = 2 * lane, e1 = 2 * lane + 1;
  const float z0 = sZs[wave][e0], z1 = sZs[wave][e1];
  const float dist0 = z1 - z0;
  const float dist1 = (lane == 63) ? 1e10f : (sZs[wave][e1 + 1] - z1);
  const float s0 = fmaxf(sSg[wave][e0], 0.f);
  const float s1 = fmaxf(sSg[wave][e1], 0.f);
  const float al0 = 1.f - expf(-s0 * dist0);
  const float al1 = 1.f - expf(-s1 * dist1);
  const float aa0 = 1.f - al0 + 1e-10f;
  const float aa1 = 1.f - al1 + 1e-10f;
  float Pp = scan_mul(aa0 * aa1, lane);
  float Tp = __shfl_up(Pp, 1, 64);
  if (lane == 0) Tp = 1.f;
  const float w0 = al0 * Tp;
  const float w1 = al1 * Tp * aa0;

  float accR = w0 * sRg[wave][e0 * 3 + 0] + w1 * sRg[wave][e1 * 3 + 0];
  float accG = w0 * sRg[wave][e0 * 3 + 1] + w1 * sRg[wave][e1 * 3 + 1];
  float accB = w0 * sRg[wave][e0 * 3 + 2] + w1 * sRg[wave][e1 * 3 + 2];
  float accD = w0 * z0 + w1 * z1;
  float accM = w0 + w1;
  accR = reduce_add(accR);
  accG = reduce_add(accG);
  accB = reduce_add(accB);
  accD = reduce_add(accD);
  accM = reduce_add(accM);

  if (lane == 0) {
    // camera-space depth: -(sum_j rd_j * T[b, j, 2]) * depth
    const float* tf = tform + (ray >> 12) * 16;
    const float vz = d0 * tf[2] + d1 * tf[6] + d2 * tf[10];
    out[ray * 3 + 0]     = accR;
    out[ray * 3 + 1]     = accG;
    out[ray * 3 + 2]     = accB;
    out[NRAYS * 3 + ray] = -vz * accD;
    out[NRAYS * 4 + ray] = accM;
  }
}

extern "C" void kernel_launch(void* const* d_in, const int* in_sizes, int n_in,
                              void* d_out, int out_size, void* d_ws, size_t ws_size,
                              hipStream_t stream) {
  const float* ray_o = (const float*)d_in[0];
  const float* ray_d = (const float*)d_in[1];
  const float* tform = (const float*)d_in[2];
  const float* noise = (const float*)d_in[3];
  const float* usmp  = (const float*)d_in[4];
  const float* W1    = (const float*)d_in[5];
  const float* b1    = (const float*)d_in[6];
  const float* W2    = (const float*)d_in[7];
  const float* b2    = (const float*)d_in[8];
  float* out = (float*)d_out;

  nerf_fused<<<dim3(NRAYS / RPB), RPB * 64, 0, stream>>>(
      ray_o, ray_d, tform, noise, usmp, W1, b1, W2, b2, out);
}

// Round 2
// 139.659 us; speedup vs baseline: 1.1541x; 1.1541x over previous
//
#include <hip/hip_runtime.h>
#include <math.h>

#define Nn    64
#define RPB   4
#define NRAYS 16384
#define NEARV 2.0f
#define FARV  6.0f

typedef __attribute__((ext_vector_type(8))) short bf16x8;
typedef __attribute__((ext_vector_type(4))) float f32x4;

__device__ __forceinline__ float scan_mul(float p, int lane) {
#pragma unroll
  for (int off = 1; off < 64; off <<= 1) {
    float t = __shfl_up(p, off, 64);
    if (lane >= off) p *= t;
  }
  return p;
}
__device__ __forceinline__ float scan_add(float v, int lane) {
#pragma unroll
  for (int off = 1; off < 64; off <<= 1) {
    float t = __shfl_up(v, off, 64);
    if (lane >= off) v += t;
  }
  return v;
}
__device__ __forceinline__ float reduce_add(float v) {
#pragma unroll
  for (int off = 32; off > 0; off >>= 1) v += __shfl_xor(v, off, 64);
  return v;
}
__device__ __forceinline__ float sigmoidf(float x) { return 1.f / (1.f + expf(-x)); }

// bf16 truncation split: x = hi + resid, hi exactly representable in bf16
__device__ __forceinline__ short bfhi_bits(float x) {
  return (short)(__float_as_uint(x) >> 16);
}
__device__ __forceinline__ float bfhi_val(float x) {
  return __uint_as_float(__float_as_uint(x) & 0xFFFF0000u);
}

// Field eval for 64 samples per ray via MFMA: D = W2^T(4x64) @ h^T(64x64).
// A[m=lane&15][k=quad*8+j] = W2[k][m]; B[k=quad*8+j][n=lane&15] = h[sample n][k].
// D: col=lane&15 (sample within tile), row=(lane>>4)*4+reg (output idx; valid rows 0..3 live in quad 0).
__device__ __forceinline__ void field_eval(
    float zlane, const float c0r[2][8], const float c1r[2][8],
    const bf16x8 aHi[2], const bf16x8 aLo[2],
    float b20, float b21, float b22, float b23,
    int quad, int col, float o[4]) {
  f32x4 acc[4];
  const bool q0 = (quad == 0);
#pragma unroll
  for (int nt = 0; nt < 4; ++nt) {
    acc[nt][0] = q0 ? b20 : 0.f;
    acc[nt][1] = q0 ? b21 : 0.f;
    acc[nt][2] = q0 ? b22 : 0.f;
    acc[nt][3] = q0 ? b23 : 0.f;
  }
#pragma unroll
  for (int nt = 0; nt < 4; ++nt) {
    const float zm = __shfl(zlane, nt * 16 + col, 64);
#pragma unroll
    for (int ks = 0; ks < 2; ++ks) {
      bf16x8 bHi, bLo;
#pragma unroll
      for (int j = 0; j < 8; ++j) {
        float h = fmaf(zm, c1r[ks][j], c0r[ks][j]);
        h = fmaxf(h, 0.f);
        const float hh = bfhi_val(h);
        bHi[j] = bfhi_bits(h);
        bLo[j] = bfhi_bits(h - hh);
      }
      acc[nt] = __builtin_amdgcn_mfma_f32_16x16x32_bf16(aHi[ks], bHi, acc[nt], 0, 0, 0);
      acc[nt] = __builtin_amdgcn_mfma_f32_16x16x32_bf16(aHi[ks], bLo, acc[nt], 0, 0, 0);
      acc[nt] = __builtin_amdgcn_mfma_f32_16x16x32_bf16(aLo[ks], bHi, acc[nt], 0, 0, 0);
    }
  }
  // redistribute: sample s=lane lives in lane (s&15)=col, tile nt=(s>>4)=quad, regs 0..3
#pragma unroll
  for (int nt = 0; nt < 4; ++nt) {
    const float t0 = __shfl(acc[nt][0], col, 64);
    const float t1 = __shfl(acc[nt][1], col, 64);
    const float t2 = __shfl(acc[nt][2], col, 64);
    const float t3 = __shfl(acc[nt][3], col, 64);
    if (quad == nt) { o[0] = t0; o[1] = t1; o[2] = t2; o[3] = t3; }
  }
}

__global__ __launch_bounds__(RPB * 64) void nerf_fused(
    const float* __restrict__ ray_o, const float* __restrict__ ray_d,
    const float* __restrict__ tform, const float* __restrict__ noise,
    const float* __restrict__ usmp,  const float* __restrict__ W1,
    const float* __restrict__ b1,    const float* __restrict__ W2,
    const float* __restrict__ b2,    float* __restrict__ out) {
  const int wave = threadIdx.x >> 6;
  const int lane = threadIdx.x & 63;
  const int ray  = blockIdx.x * RPB + wave;
  const int quad = lane >> 4;
  const int col  = lane & 15;

  __shared__ float2 sC  [RPB][Nn];       // (c0,c1) per hidden unit
  __shared__ float  sZc [RPB][Nn];       // coarse z (sorted by construction)
  __shared__ float  sCdf[RPB][Nn];
  __shared__ float  sBin[RPB][Nn];
  __shared__ float  sFs [RPB][Nn];       // sorted fine z
  __shared__ float  sZs [RPB][2 * Nn];   // merged sorted z
  __shared__ float4 sPk [RPB][2 * Nn];   // merged (sigma, r, g, b)

  // ---- per-ray constants ----
  const float o0 = ray_o[ray * 3 + 0], o1 = ray_o[ray * 3 + 1], o2 = ray_o[ray * 3 + 2];
  float d0 = ray_d[ray * 3 + 0], d1 = ray_d[ray * 3 + 1], d2 = ray_d[ray * 3 + 2];
  const float nrm = sqrtf(d0 * d0 + d1 * d1 + d2 * d2);
  d0 /= nrm; d1 /= nrm; d2 /= nrm;

  // lane j builds record j: h_j(z) = relu(z*c1 + c0)
  {
    const float w10 = W1[lane], w11 = W1[64 + lane], w12 = W1[128 + lane];
    const float c1 = d0 * w10 + d1 * w11 + d2 * w12;
    const float c0 = o0 * w10 + o1 * w11 + o2 * w12 + b1[lane];
    sC[wave][lane] = make_float2(c0, c1);
  }

  // coarse z (strictly increasing in lane)
  const float nz = noise[ray * Nn + lane];
  const float z  = NEARV + (FARV - NEARV) * ((float)lane + nz) * (1.0f / Nn);
  sZc[wave][lane] = z;
  __syncthreads();

  // hoist (c0,c1) fragments for this lane's k-range: k = ks*32 + quad*8 + j
  float c0r[2][8], c1r[2][8];
#pragma unroll
  for (int ks = 0; ks < 2; ++ks) {
    const float4* cc4 = (const float4*)&sC[wave][0];
    const int base4 = (ks * 32 + quad * 8) >> 1;   // float4 index (2 pairs each)
#pragma unroll
    for (int jj = 0; jj < 4; ++jj) {
      const float4 v = cc4[base4 + jj];
      c0r[ks][2 * jj]     = v.x;  c1r[ks][2 * jj]     = v.y;
      c0r[ks][2 * jj + 1] = v.z;  c1r[ks][2 * jj + 1] = v.w;
    }
  }

  // A-fragments: W2^T, bf16 hi/lo split (built once per ray)
  bf16x8 aHi[2], aLo[2];
#pragma unroll
  for (int ks = 0; ks < 2; ++ks) {
#pragma unroll
    for (int j = 0; j < 8; ++j) {
      const int k = ks * 32 + quad * 8 + j;
      const float wv  = (col < 4) ? W2[k * 4 + col] : 0.f;
      const float whi = bfhi_val(wv);
      aHi[ks][j] = bfhi_bits(wv);
      aLo[ks][j] = bfhi_bits(wv - whi);
    }
  }
  const float b20 = b2[0], b21 = b2[1], b22 = b2[2], b23 = b2[3];

  // ---- coarse field eval ----
  float oc[4];
  field_eval(z, c0r, c1r, aHi, aLo, b20, b21, b22, b23, quad, col, oc);
  const float sig = oc[0];
  const float cr = sigmoidf(oc[1]), cg = sigmoidf(oc[2]), cb = sigmoidf(oc[3]);

  // ---- coarse compositing weights + smoothed pdf/cdf ----
  const float zn   = __shfl_down(z, 1, 64);
  const float dist = (lane == 63) ? 1e10f : (zn - z);
  const float alpha = 1.f - expf(-fmaxf(sig, 0.f) * dist);
  {
    float P  = scan_mul(1.f - alpha + 1e-10f, lane);
    float Te = __shfl_up(P, 1, 64);
    if (lane == 0) Te = 1.f;
    const float w = alpha * Te;

    const float wp = __shfl_up(w, 1, 64);
    const float wn = __shfl_down(w, 1, 64);
    const float mxA = (lane == 0)  ? w : fmaxf(wp, w);
    const float mxB = (lane == 63) ? w : fmaxf(w, wn);
    const float sm = 0.5f * (mxA + mxB) + 0.01f;

    const float v   = (lane >= 1 && lane <= 62) ? sm : 0.f;
    const float tot = reduce_add(v);
    const float pdf = v / tot;
    const float C   = scan_add(pdf, lane);
    sCdf[wave][lane] = (lane == 0) ? 0.f : C;
    sBin[wave][lane] = 0.5f * (z + zn);
  }
  __syncthreads();

  // ---- inverse-CDF sampling (searchsorted side='right') ----
  const float u = usmp[ray * Nn + lane];
  int lo = 0, hi = 63;
  while (lo < hi) {
    const int mid = (lo + hi) >> 1;
    if (sCdf[wave][mid] <= u) lo = mid + 1; else hi = mid;
  }
  const int below = lo - 1;
  const int above = (lo < 63) ? lo : 62;
  const float cdfb = sCdf[wave][below], cdfa = sCdf[wave][above];
  const float binb = sBin[wave][below], bina = sBin[wave][above];
  float den = cdfa - cdfb;
  if (den < 1e-5f) den = 1.f;
  const float zs = fmaf((u - cdfb) / den, bina - binb, binb);

  // ---- fine field eval ----
  float of[4];
  field_eval(zs, c0r, c1r, aHi, aLo, b20, b21, b22, b23, quad, col, of);
  const float sigF = of[0];
  const float fr = sigmoidf(of[1]), fg = sigmoidf(of[2]), fb = sigmoidf(of[3]);

  // ---- stable merge of sorted coarse + fine ----
  // rank among fine (stable by original index)
  int r1 = 0;
#pragma unroll
  for (int j = 0; j < 64; ++j) {
    const float zj = __shfl(zs, j, 64);
    r1 += ((zj < zs) || (zj == zs && j < lane)) ? 1 : 0;
  }
  // count coarse <= zs (coarse wins ties: coarse original idx < fine idx)
  int lo1 = 0, hi1 = 64;
  while (lo1 < hi1) {
    const int mid = (lo1 + hi1) >> 1;
    if (sZc[wave][mid] <= zs) lo1 = mid + 1; else hi1 = mid;
  }
  const int p1 = r1 + lo1;
  sFs[wave][r1] = zs;
  __syncthreads();
  // count fine < z (strict)
  int lo2 = 0, hi2 = 64;
  while (lo2 < hi2) {
    const int mid = (lo2 + hi2) >> 1;
    if (sFs[wave][mid] < z) lo2 = mid + 1; else hi2 = mid;
  }
  const int p0 = lane + lo2;

  sZs[wave][p0] = z;
  sZs[wave][p1] = zs;
  sPk[wave][p0] = make_float4(sig,  cr, cg, cb);
  sPk[wave][p1] = make_float4(sigF, fr, fg, fb);
  __syncthreads();

  // ---- final compositing over 128 sorted samples (2 per lane) ----
  const float2 zz = *(const float2*)&sZs[wave][2 * lane];
  const float z0 = zz.x, z1 = zz.y;
  const float z2 = __shfl_down(z0, 1, 64);
  const float dist0 = z1 - z0;
  const float dist1 = (lane == 63) ? 1e10f : (z2 - z1);
  const float4 q0 = sPk[wave][2 * lane];
  const float4 q1 = sPk[wave][2 * lane + 1];
  const float al0 = 1.f - expf(-fmaxf(q0.x, 0.f) * dist0);
  const float al1 = 1.f - expf(-fmaxf(q1.x, 0.f) * dist1);
  const float aa0 = 1.f - al0 + 1e-10f;
  const float aa1 = 1.f - al1 + 1e-10f;
  float Pp = scan_mul(aa0 * aa1, lane);
  float Tp = __shfl_up(Pp, 1, 64);
  if (lane == 0) Tp = 1.f;
  const float w0 = al0 * Tp;
  const float w1 = al1 * Tp * aa0;

  float accR = w0 * q0.y + w1 * q1.y;
  float accG = w0 * q0.z + w1 * q1.z;
  float accB = w0 * q0.w + w1 * q1.w;
  float accD = w0 * z0 + w1 * z1;
  float accM = w0 + w1;
  accR = reduce_add(accR);
  accG = reduce_add(accG);
  accB = reduce_add(accB);
  accD = reduce_add(accD);
  accM = reduce_add(accM);

  if (lane == 0) {
    const float* tf = tform + (ray >> 12) * 16;
    const float vz = d0 * tf[2] + d1 * tf[6] + d2 * tf[10];
    out[ray * 3 + 0]     = accR;
    out[ray * 3 + 1]     = accG;
    out[ray * 3 + 2]     = accB;
    out[NRAYS * 3 + ray] = -vz * accD;
    out[NRAYS * 4 + ray] = accM;
  }
}

extern "C" void kernel_launch(void* const* d_in, const int* in_sizes, int n_in,
                              void* d_out, int out_size, void* d_ws, size_t ws_size,
                              hipStream_t stream) {
  const float* ray_o = (const float*)d_in[0];
  const float* ray_d = (const float*)d_in[1];
  const float* tform = (const float*)d_in[2];
  const float* noise = (const float*)d_in[3];
  const float* usmp  = (const float*)d_in[4];
  const float* W1    = (const float*)d_in[5];
  const float* b1    = (const float*)d_in[6];
  const float* W2    = (const float*)d_in[7];
  const float* b2    = (const float*)d_in[8];
  float* out = (float*)d_out;

  nerf_fused<<<dim3(NRAYS / RPB), RPB * 64, 0, stream>>>(
      ray_o, ray_d, tform, noise, usmp, W1, b1, W2, b2, out);
}

// Round 4
// 136.876 us; speedup vs baseline: 1.1776x; 1.0203x over previous
//
#include <hip/hip_runtime.h>
#include <hip/hip_bf16.h>
#include <math.h>

#define Nn    64
#define RPB   4
#define NRAYS 16384
#define NEARV 2.0f
#define FARV  6.0f

typedef __attribute__((ext_vector_type(8))) short bf16x8;
typedef __attribute__((ext_vector_type(4))) float f32x4;

__device__ __forceinline__ float scan_mul(float p, int lane) {
#pragma unroll
  for (int off = 1; off < 64; off <<= 1) {
    float t = __shfl_up(p, off, 64);
    if (lane >= off) p *= t;
  }
  return p;
}
__device__ __forceinline__ float scan_add(float v, int lane) {
#pragma unroll
  for (int off = 1; off < 64; off <<= 1) {
    float t = __shfl_up(v, off, 64);
    if (lane >= off) v += t;
  }
  return v;
}
__device__ __forceinline__ float reduce_add(float v) {
#pragma unroll
  for (int off = 32; off > 0; off >>= 1) v += __shfl_xor(v, off, 64);
  return v;
}

__device__ __forceinline__ float fast_rcp(float x) { return __builtin_amdgcn_rcpf(x); }
__device__ __forceinline__ float sigmoidf_fast(float x) {
  return fast_rcp(1.f + __expf(-x));
}

// bf16 truncation split helpers (prologue only)
__device__ __forceinline__ short bfhi_bits(float x) {
  return (short)(__float_as_uint(x) >> 16);
}
__device__ __forceinline__ float bfhi_val(float x) {
  return __uint_as_float(__float_as_uint(x) & 0xFFFF0000u);
}

// Field eval for 64 samples per ray via MFMA: D = W2^T(4x64) @ h^T(64x64).
// Precision: truncation split A = Ahi+Alo, B = Bhi+Blo; accumulate
// Ahi*Bhi + Ahi*Blo + Alo*Bhi (drop Alo*Blo ~2^-18) -> known absmax 0.0156.
// D: col=lane&15 (sample in tile), row=(lane>>4)*4+reg; valid rows 0..3 in quad 0.
__device__ __forceinline__ void field_eval(
    float zlane, const float c0r[2][8], const float c1r[2][8],
    const bf16x8 aHi[2], const bf16x8 aLo[2],
    float b20, float b21, float b22, float b23,
    int quad, int col, float o[4]) {
  f32x4 acc[4];
  const bool q0 = (quad == 0);
#pragma unroll
  for (int nt = 0; nt < 4; ++nt) {
    acc[nt][0] = q0 ? b20 : 0.f;
    acc[nt][1] = q0 ? b21 : 0.f;
    acc[nt][2] = q0 ? b22 : 0.f;
    acc[nt][3] = q0 ? b23 : 0.f;
  }
#pragma unroll
  for (int nt = 0; nt < 4; ++nt) {
    const float zm = __shfl(zlane, nt * 16 + col, 64);
#pragma unroll
    for (int ks = 0; ks < 2; ++ks) {
      union { bf16x8 v; unsigned int u[4]; } Bhi, Blo;
#pragma unroll
      for (int p = 0; p < 4; ++p) {
        const float h0 = fmaxf(fmaf(zm, c1r[ks][2 * p],     c0r[ks][2 * p]),     0.f);
        const float h1 = fmaxf(fmaf(zm, c1r[ks][2 * p + 1], c0r[ks][2 * p + 1]), 0.f);
        const unsigned uh0 = __float_as_uint(h0);
        const unsigned uh1 = __float_as_uint(h1);
        // (h1.hi16 << 16) | h0.hi16 in one v_perm_b32
        Bhi.u[p] = __builtin_amdgcn_perm(uh1, uh0, 0x07060302u);
        const float l0 = h0 - __uint_as_float(uh0 & 0xFFFF0000u);
        const float l1 = h1 - __uint_as_float(uh1 & 0xFFFF0000u);
        Blo.u[p] = __builtin_amdgcn_perm(__float_as_uint(l1), __float_as_uint(l0), 0x07060302u);
      }
      acc[nt] = __builtin_amdgcn_mfma_f32_16x16x32_bf16(aHi[ks], Bhi.v, acc[nt], 0, 0, 0);
      acc[nt] = __builtin_amdgcn_mfma_f32_16x16x32_bf16(aHi[ks], Blo.v, acc[nt], 0, 0, 0);
      acc[nt] = __builtin_amdgcn_mfma_f32_16x16x32_bf16(aLo[ks], Bhi.v, acc[nt], 0, 0, 0);
    }
  }
  // redistribute: sample s=lane lives in lane (s&15)=col of tile nt=(s>>4), regs 0..3
#pragma unroll
  for (int nt = 0; nt < 4; ++nt) {
    const float t0 = __shfl(acc[nt][0], col, 64);
    const float t1 = __shfl(acc[nt][1], col, 64);
    const float t2 = __shfl(acc[nt][2], col, 64);
    const float t3 = __shfl(acc[nt][3], col, 64);
    if (quad == nt) { o[0] = t0; o[1] = t1; o[2] = t2; o[3] = t3; }
  }
}

__global__ __launch_bounds__(RPB * 64) void nerf_fused(
    const float* __restrict__ ray_o, const float* __restrict__ ray_d,
    const float* __restrict__ tform, const float* __restrict__ noise,
    const float* __restrict__ usmp,  const float* __restrict__ W1,
    const float* __restrict__ b1,    const float* __restrict__ W2,
    const float* __restrict__ b2,    float* __restrict__ out) {
  const int wave = threadIdx.x >> 6;
  const int lane = threadIdx.x & 63;
  const int ray  = blockIdx.x * RPB + wave;
  const int quad = lane >> 4;
  const int col  = lane & 15;

  __shared__ float2 sC  [RPB][Nn];       // (c0,c1) per hidden unit
  __shared__ float  sZc [RPB][Nn];       // coarse z (sorted by construction)
  __shared__ float  sCdf[RPB][Nn];
  __shared__ float  sBin[RPB][Nn];
  __shared__ float  sFs [RPB][Nn];       // sorted fine z
  __shared__ float  sZs [RPB][2 * Nn];   // merged sorted z
  __shared__ float4 sPk [RPB][2 * Nn];   // merged (sigma, r, g, b)

  // ---- per-ray constants ----
  const float o0 = ray_o[ray * 3 + 0], o1 = ray_o[ray * 3 + 1], o2 = ray_o[ray * 3 + 2];
  float d0 = ray_d[ray * 3 + 0], d1 = ray_d[ray * 3 + 1], d2 = ray_d[ray * 3 + 2];
  const float rn = __builtin_amdgcn_rsqf(d0 * d0 + d1 * d1 + d2 * d2);
  d0 *= rn; d1 *= rn; d2 *= rn;

  // lane j builds record j: h_j(z) = relu(z*c1 + c0)
  {
    const float w10 = W1[lane], w11 = W1[64 + lane], w12 = W1[128 + lane];
    const float c1 = d0 * w10 + d1 * w11 + d2 * w12;
    const float c0 = o0 * w10 + o1 * w11 + o2 * w12 + b1[lane];
    sC[wave][lane] = make_float2(c0, c1);
  }

  // coarse z (strictly increasing in lane)
  const float nz = noise[ray * Nn + lane];
  const float z  = NEARV + (FARV - NEARV) * ((float)lane + nz) * (1.0f / Nn);
  sZc[wave][lane] = z;
  __syncthreads();

  // hoist (c0,c1) fragments for this lane's k-range: k = ks*32 + quad*8 + j
  float c0r[2][8], c1r[2][8];
#pragma unroll
  for (int ks = 0; ks < 2; ++ks) {
    const float4* cc4 = (const float4*)&sC[wave][0];
    const int base4 = (ks * 32 + quad * 8) >> 1;
#pragma unroll
    for (int jj = 0; jj < 4; ++jj) {
      const float4 v = cc4[base4 + jj];
      c0r[ks][2 * jj]     = v.x;  c1r[ks][2 * jj]     = v.y;
      c0r[ks][2 * jj + 1] = v.z;  c1r[ks][2 * jj + 1] = v.w;
    }
  }

  // A-fragments: W2^T, bf16 hi/lo truncation split (built once per ray)
  bf16x8 aHi[2], aLo[2];
#pragma unroll
  for (int ks = 0; ks < 2; ++ks) {
#pragma unroll
    for (int j = 0; j < 8; ++j) {
      const int k = ks * 32 + quad * 8 + j;
      const float wv  = (col < 4) ? W2[k * 4 + col] : 0.f;
      const float whi = bfhi_val(wv);
      aHi[ks][j] = bfhi_bits(wv);
      aLo[ks][j] = bfhi_bits(wv - whi);
    }
  }
  const float b20 = b2[0], b21 = b2[1], b22 = b2[2], b23 = b2[3];

  // ---- coarse field eval ----
  float oc[4];
  field_eval(z, c0r, c1r, aHi, aLo, b20, b21, b22, b23, quad, col, oc);
  const float sig = oc[0];
  const float cr = sigmoidf_fast(oc[1]), cg = sigmoidf_fast(oc[2]), cb = sigmoidf_fast(oc[3]);

  // ---- coarse compositing weights + smoothed pdf/cdf ----
  const float zn   = __shfl_down(z, 1, 64);
  const float dist = (lane == 63) ? 1e10f : (zn - z);
  const float alpha = 1.f - __expf(-fmaxf(sig, 0.f) * dist);
  {
    float P  = scan_mul(1.f - alpha + 1e-10f, lane);
    float Te = __shfl_up(P, 1, 64);
    if (lane == 0) Te = 1.f;
    const float w = alpha * Te;

    const float wp = __shfl_up(w, 1, 64);
    const float wn = __shfl_down(w, 1, 64);
    const float mxA = (lane == 0)  ? w : fmaxf(wp, w);
    const float mxB = (lane == 63) ? w : fmaxf(w, wn);
    const float sm = 0.5f * (mxA + mxB) + 0.01f;

    const float v   = (lane >= 1 && lane <= 62) ? sm : 0.f;
    const float tot = reduce_add(v);
    const float pdf = v * fast_rcp(tot);
    const float C   = scan_add(pdf, lane);
    sCdf[wave][lane] = (lane == 0) ? 0.f : C;
    sBin[wave][lane] = 0.5f * (z + zn);
  }
  __syncthreads();

  // ---- inverse-CDF sampling (searchsorted side='right') ----
  const float u = usmp[ray * Nn + lane];
  int lo = 0, hi = 63;
  while (lo < hi) {
    const int mid = (lo + hi) >> 1;
    if (sCdf[wave][mid] <= u) lo = mid + 1; else hi = mid;
  }
  const int below = lo - 1;
  const int above = (lo < 63) ? lo : 62;
  const float cdfb = sCdf[wave][below], cdfa = sCdf[wave][above];
  const float binb = sBin[wave][below], bina = sBin[wave][above];
  float den = cdfa - cdfb;
  if (den < 1e-5f) den = 1.f;
  const float zs = fmaf((u - cdfb) * fast_rcp(den), bina - binb, binb);

  // ---- fine field eval ----
  float of[4];
  field_eval(zs, c0r, c1r, aHi, aLo, b20, b21, b22, b23, quad, col, of);
  const float sigF = of[0];
  const float fr = sigmoidf_fast(of[1]), fg = sigmoidf_fast(of[2]), fb = sigmoidf_fast(of[3]);

  // ---- stable merge of sorted coarse + fine ----
  int r1 = 0;
#pragma unroll
  for (int j = 0; j < 64; ++j) {
    const float zj = __shfl(zs, j, 64);
    r1 += ((zj < zs) || (zj == zs && j < lane)) ? 1 : 0;
  }
  int lo1 = 0, hi1 = 64;
  while (lo1 < hi1) {
    const int mid = (lo1 + hi1) >> 1;
    if (sZc[wave][mid] <= zs) lo1 = mid + 1; else hi1 = mid;
  }
  const int p1 = r1 + lo1;
  sFs[wave][r1] = zs;
  __syncthreads();
  int lo2 = 0, hi2 = 64;
  while (lo2 < hi2) {
    const int mid = (lo2 + hi2) >> 1;
    if (sFs[wave][mid] < z) lo2 = mid + 1; else hi2 = mid;
  }
  const int p0 = lane + lo2;

  sZs[wave][p0] = z;
  sZs[wave][p1] = zs;
  sPk[wave][p0] = make_float4(sig,  cr, cg, cb);
  sPk[wave][p1] = make_float4(sigF, fr, fg, fb);
  __syncthreads();

  // ---- final compositing over 128 sorted samples (2 per lane) ----
  const float2 zz = *(const float2*)&sZs[wave][2 * lane];
  const float z0 = zz.x, z1 = zz.y;
  const float z2 = __shfl_down(z0, 1, 64);
  const float dist0 = z1 - z0;
  const float dist1 = (lane == 63) ? 1e10f : (z2 - z1);
  const float4 q0 = sPk[wave][2 * lane];
  const float4 q1 = sPk[wave][2 * lane + 1];
  const float al0 = 1.f - __expf(-fmaxf(q0.x, 0.f) * dist0);
  const float al1 = 1.f - __expf(-fmaxf(q1.x, 0.f) * dist1);
  const float aa0 = 1.f - al0 + 1e-10f;
  const float aa1 = 1.f - al1 + 1e-10f;
  float Pp = scan_mul(aa0 * aa1, lane);
  float Tp = __shfl_up(Pp, 1, 64);
  if (lane == 0) Tp = 1.f;
  const float w0 = al0 * Tp;
  const float w1 = al1 * Tp * aa0;

  float accR = w0 * q0.y + w1 * q1.y;
  float accG = w0 * q0.z + w1 * q1.z;
  float accB = w0 * q0.w + w1 * q1.w;
  float accD = w0 * z0 + w1 * z1;
  float accM = w0 + w1;
  accR = reduce_add(accR);
  accG = reduce_add(accG);
  accB = reduce_add(accB);
  accD = reduce_add(accD);
  accM = reduce_add(accM);

  if (lane == 0) {
    const float* tf = tform + (ray >> 12) * 16;
    const float vz = d0 * tf[2] + d1 * tf[6] + d2 * tf[10];
    out[ray * 3 + 0]     = accR;
    out[ray * 3 + 1]     = accG;
    out[ray * 3 + 2]     = accB;
    out[NRAYS * 3 + ray] = -vz * accD;
    out[NRAYS * 4 + ray] = accM;
  }
}

extern "C" void kernel_launch(void* const* d_in, const int* in_sizes, int n_in,
                              void* d_out, int out_size, void* d_ws, size_t ws_size,
                              hipStream_t stream) {
  const float* ray_o = (const float*)d_in[0];
  const float* ray_d = (const float*)d_in[1];
  const float* tform = (const float*)d_in[2];
  const float* noise = (const float*)d_in[3];
  const float* usmp  = (const float*)d_in[4];
  const float* W1    = (const float*)d_in[5];
  const float* b1    = (const float*)d_in[6];
  const float* W2    = (const float*)d_in[7];
  const float* b2    = (const float*)d_in[8];
  float* out = (float*)d_out;

  nerf_fused<<<dim3(NRAYS / RPB), RPB * 64, 0, stream>>>(
      ray_o, ray_d, tform, noise, usmp, W1, b1, W2, b2, out);
}